// Round 6
// baseline (343.081 us; speedup 1.0000x reference)
//
#include <hip/hip_runtime.h>

// SimpleHashEncoder1D: out[n, l*2+f] = hash_table[floor(xn*scale[l]+0.5) & (T-1)][f]
// xn = (x+bound)/(2*bound), scale[l] = 16*b^l - 1
//
// float32 bit-exactness (verified R1..R8, absmax == 0.0):
//   bits(scale[l]) = ((130+l)<<23) | (0x800000 - (0x100000>>l) - l)
//   separate mul/add (no contraction), __fdiv_rn normalize, trunc==floor,
//   '&(T-1)' == '%T' since idx < 2^19.
//
// Ledger: R4 338 (4x MLP) best; R5 nt/plain stores neutral; R6 sc0-all +32;
// R7 selective sc0 neutral; R8 LDS-serving levels 0-10 neutral. Surviving
// theory: the wall is ~1.34 GB of 128 B LINE-FILL traffic from the 10.5 M
// truly-random gathers of levels 11-15 (L2<-L3 fills; request count, L1
// flavor, and MLP depth are all irrelevant to it — matching all 6 results).
// But reuse exists: level 15 has 2^15 lines for 2^21 points = 64 pts/line.
//
// R9: BIN-THEN-ENCODE. K1 bins points into 256 x-buckets (fixed-capacity
// regions, LDS-aggregated reservations, no prefix kernel). K2 = exact R4
// arithmetic over binned order: a 1024-thr block covers 128 slots of ONE
// bucket -> fine-level line working set ~32 KB (L1-resident; XCD-swizzled
// so each XCD's L2 sees only its buckets' ~1 MB table panel). out[n] wrtten
// as full 128 B lines (8 lanes per point) -> same store segment count as
// R4. Output bits identical: K2 recomputes from verbatim x bits.
// Falls back to the proven R4 kernel if ws_size < ~21 MB.

constexpr int T_SIZE = 524288;   // 2^19
constexpr int N_PTS  = 2097152;  // 2^21
constexpr int NB     = 256;      // x-buckets
constexpr int CAP    = 10240;    // slots/bucket = mean 8192 + 22 sigma; mult of 128
constexpr int CSTR   = 32;       // cursor stride in ints (128 B: one line/slice each)
constexpr size_t WS_NEED = 32768 + (size_t)NB * CAP * 8;  // cursors + pairs

typedef float vfloat4 __attribute__((ext_vector_type(4)));

__device__ __forceinline__ float scale_for_level(int l) {
    unsigned bits = ((130u + (unsigned)l) << 23)
                  | (0x800000u - (0x100000u >> l) - (unsigned)l);
    return __uint_as_float(bits);
}

// ---------------- K0: init bucket cursors ----------------
__global__ void k0_init(int* __restrict__ cursor) {
    int b = threadIdx.x;            // 256 threads
    cursor[b * CSTR] = b * CAP;
}

// ---------------- K1: bin points into bucket regions ----------------
// 256 blocks x 1024 thr; block g owns points [g*8192, (g+1)*8192).
__global__ __launch_bounds__(1024) void k1_bin(
    const float* __restrict__ x,
    const int* __restrict__ bound_p,
    int* __restrict__ cursor,
    uint2* __restrict__ pairs)
{
    __shared__ int lhist[NB];
    __shared__ int lbase[NB];
    int t = threadIdx.x;
    if (t < NB) lhist[t] = 0;
    __syncthreads();

    float fb  = (float)bound_p[0];
    float fb2 = __fmul_rn(2.0f, fb);
    int base = blockIdx.x * 8192;

    unsigned xb[8]; int bk[8]; int lr[8];
#pragma unroll
    for (int i = 0; i < 8; ++i) {
        int n = base + t + i * 1024;
        float xv = x[n];
        xb[i] = __float_as_uint(xv);
        float xn = __fdiv_rn(__fadd_rn(xv, fb), fb2);   // [0,1]
        int b = (int)(xn * 256.0f);
        b = b < 0 ? 0 : (b > 255 ? 255 : b);
        bk[i] = b;
        lr[i] = atomicAdd(&lhist[b], 1);   // rank within block (any order ok)
    }
    __syncthreads();
    if (t < NB) lbase[t] = atomicAdd(&cursor[t * CSTR], lhist[t]);
    __syncthreads();
#pragma unroll
    for (int i = 0; i < 8; ++i) {
        int n = base + t + i * 1024;
        int pos = lbase[bk[i]] + lr[i];    // unique slot in bucket region
        pairs[pos] = make_uint2(xb[i], (unsigned)n);
    }
}

// ---------------- K2: encode in binned order ----------------
// 20480 blocks x 1024 thr; 8 lanes per point (j = level-pair), block = 128
// slots of ONE bucket (CAP and block/8 both multiples of 128).
__global__ __launch_bounds__(1024) void k2_main(
    const uint2* __restrict__ pairs,
    const int* __restrict__ cursor,
    const float* __restrict__ table,
    const int* __restrict__ bound_p,
    float* __restrict__ out)
{
    // XCD-aware bijective swizzle (nwg=20480 divisible by 8): XCD x gets a
    // contiguous block range -> contiguous buckets -> ~1 MB table panel in
    // its private L2.
    unsigned bid = blockIdx.x;
    unsigned swz = (bid & 7u) * (20480u / 8u) + (bid >> 3);

    unsigned tid  = swz * 1024u + threadIdx.x;
    unsigned slot = tid >> 3;
    int j = tid & 7;

    int b      = (int)(slot / (unsigned)CAP);      // magic-div
    int within = (int)(slot - (unsigned)b * CAP);
    int cnt    = cursor[b * CSTR] - b * CAP;       // final bucket count
    if (within >= cnt) return;                     // tail slots: no point

    uint2 pr = pairs[slot];
    float xv   = __uint_as_float(pr.x);            // verbatim original bits
    unsigned n = pr.y;

    float fb  = (float)bound_p[0];
    float fb2 = __fmul_rn(2.0f, fb);
    float xn  = __fdiv_rn(__fadd_rn(xv, fb), fb2);

    float s0 = scale_for_level(j << 1);
    float s1 = scale_for_level((j << 1) + 1);
    float xs0 = __fadd_rn(__fmul_rn(xn, s0), 0.5f);
    float xs1 = __fadd_rn(__fmul_rn(xn, s1), 0.5f);
    int i0 = ((int)xs0) & (T_SIZE - 1);
    int i1 = ((int)xs1) & (T_SIZE - 1);

    // Gathers: block's points share one x-bucket -> per-level index windows
    // ~32 KB total across levels 11-15 -> L1/L2-resident. Plain loads.
    const float2* t2 = (const float2*)table;
    float2 a = t2[i0];
    float2 c = t2[i1];

    // Store: 8 lanes of one point cover one full 128 B line of out.
    vfloat4 o;
    o.x = a.x; o.y = a.y; o.z = c.x; o.w = c.y;
    __builtin_nontemporal_store(o, (vfloat4*)out + ((n << 3) | (unsigned)j));
}

// ---------------- Fallback: the proven R4 kernel (ws too small) ----------------
constexpr int SLOTS = N_PTS * 8;
constexpr int KI    = 4;
constexpr int NTH   = SLOTS / KI;

__global__ __launch_bounds__(256) void hash_encode_r4(
    const float* __restrict__ x,
    const float* __restrict__ table,
    const int* __restrict__ bound_p,
    float* __restrict__ out)
{
    int tid = blockIdx.x * 256 + threadIdx.x;
    int j  = tid & 7;
    float s0 = scale_for_level(j << 1);
    float s1 = scale_for_level((j << 1) + 1);
    float fb  = (float)bound_p[0];
    float fb2 = __fmul_rn(2.0f, fb);

    float xv[KI];
#pragma unroll
    for (int k = 0; k < KI; ++k)
        xv[k] = __builtin_nontemporal_load(&x[(tid + k * NTH) >> 3]);

    int i0[KI], i1[KI];
#pragma unroll
    for (int k = 0; k < KI; ++k) {
        float xn  = __fdiv_rn(__fadd_rn(xv[k], fb), fb2);
        float xs0 = __fadd_rn(__fmul_rn(xn, s0), 0.5f);
        float xs1 = __fadd_rn(__fmul_rn(xn, s1), 0.5f);
        i0[k] = ((int)xs0) & (T_SIZE - 1);
        i1[k] = ((int)xs1) & (T_SIZE - 1);
    }

    const float2* t2 = (const float2*)table;
    float2 a[KI], b[KI];
#pragma unroll
    for (int k = 0; k < KI; ++k) { a[k] = t2[i0[k]]; b[k] = t2[i1[k]]; }

#pragma unroll
    for (int k = 0; k < KI; ++k) {
        vfloat4 o;
        o.x = a[k].x; o.y = a[k].y; o.z = b[k].x; o.w = b[k].y;
        __builtin_nontemporal_store(o, (vfloat4*)out + (tid + k * NTH));
    }
}

extern "C" void kernel_launch(void* const* d_in, const int* in_sizes, int n_in,
                              void* d_out, int out_size, void* d_ws, size_t ws_size,
                              hipStream_t stream) {
    const float* x     = (const float*)d_in[0];
    const float* table = (const float*)d_in[1];
    const int*   bound = (const int*)d_in[2];
    float* out = (float*)d_out;

    if (ws_size >= WS_NEED && d_ws != nullptr) {
        int*   cursor = (int*)d_ws;
        uint2* pairs  = (uint2*)((char*)d_ws + 32768);
        k0_init<<<1, NB, 0, stream>>>(cursor);
        k1_bin<<<N_PTS / 8192, 1024, 0, stream>>>(x, bound, cursor, pairs);
        k2_main<<<(NB * CAP * 8) / 1024, 1024, 0, stream>>>(
            pairs, cursor, table, bound, out);
    } else {
        hash_encode_r4<<<NTH / 256, 256, 0, stream>>>(x, table, bound, out);
    }
}